// Round 6
// baseline (4076.730 us; speedup 1.0000x reference)
//
#include <hip/hip_runtime.h>

typedef _Float16 half8 __attribute__((ext_vector_type(8)));
typedef float float4v __attribute__((ext_vector_type(4)));
typedef unsigned short u16;
typedef unsigned int u32;

// ---------- workspace layout (bytes); total ~300 KB ----------
#define OFF_HX    ((size_t)0)        /* 2(slot)*2(d)*4(g)*8(q8)*16*32 floats = 262144 B */
#define OFF_FLAGS ((size_t)262144)   /* 1024 ints = 4096 B */
#define OFF_MASK  ((size_t)266240)   /* 32768 B */

#define LO_SCALE   2048.0f
#define LO_ISCALE  (1.0f / 2048.0f)

__device__ __forceinline__ u16 h2u(_Float16 h) {
  union { _Float16 h; u16 u; } u; u.h = h; return u.u;
}
__device__ __forceinline__ float ftanh(float x) {
  // tanh(x) = 1 - 2/(exp(2x)+1); exact saturation for large |x|
  float e = __expf(x + x);
  return 1.0f - 2.0f * __builtin_amdgcn_rcpf(e + 1.0f);
}
__device__ __forceinline__ float clamp30(float v) {
  // NaN-proof diagnostic guard; never triggers on sane data (|z| <~ 8)
  return fminf(30.0f, fmaxf(-30.0f, v));
}
// split v = hi + lo/2048 (lo pre-scaled so it never hits f16 subnormals)
__device__ __forceinline__ void split2(float v, _Float16& hi, _Float16& lo) {
  hi = (_Float16)v;
  lo = (_Float16)((v - (float)hi) * LO_SCALE);
}

// ---------------- mask[t][b] = any(x[b,t,:] != 0); also zero flags ----------------
__global__ __launch_bounds__(256) void k_mask(const float* __restrict__ x,
                                              unsigned char* __restrict__ mask,
                                              int* __restrict__ flags) {
  if (blockIdx.x < 4) flags[blockIdx.x * 256 + threadIdx.x] = 0;
  int w = threadIdx.x >> 6, l = threadIdx.x & 63;
  int row = blockIdx.x * 4 + w;  // row = b*512 + t, 0..32767
  const float4v* p = (const float4v*)(x + (size_t)row * 256 + l * 4);
  float4v v = *p;
  int nz = (v[0] != 0.f) || (v[1] != 0.f) || (v[2] != 0.f) || (v[3] != 0.f);
  unsigned long long bal = __ballot(nz);
  if (l == 0) {
    int b = row >> 9, t = row & 511;
    mask[t * 64 + b] = (bal != 0ull) ? 1 : 0;
  }
}

// ---------------- fused sequential scan, split-f16 (fp32-grade), fp32 out ----------------
// 64 WGs: bid = q8*8 + (d*4+g). All 8 octant-WGs of a scan group share one XCD
// under round-robin bid&7 (latency heuristic only, not correctness).
// 256 thr / 4 waves per WG; wave w: gate pair p=w>>1 (gates 2p,2p+1),
// unit half-slice sl=w&1 (16 units of the WG's 32-unit octant q8).
// Every operand is hi(f16) + lo(f16)/2048; z = hi@hi + (hi@lo + lo@hi)/2048.
__global__ __launch_bounds__(256, 1) void k_scan(const float* __restrict__ Wk_f,
                                                 const float* __restrict__ Wr_f,
                                                 const float* __restrict__ b_f,
                                                 const float* __restrict__ Wk_b,
                                                 const float* __restrict__ Wr_b,
                                                 const float* __restrict__ b_b,
                                                 const float* __restrict__ x,
                                                 const unsigned char* __restrict__ mask,
                                                 float* __restrict__ hx,
                                                 int* __restrict__ flags,
                                                 float* __restrict__ out) {
  __shared__ u16 hhi[16][264], hlo[16][264];       // f16 bits, full 256 units
  __shared__ u16 xhi[2][16][264], xlo[2][16][264]; // f16 x tile, double-buffered
  __shared__ float zb[4][16][34];                  // [gate][row][unitcol+pad]

  int bid = blockIdx.x;
  int sg = bid & 7, q8 = bid >> 3;
  int d = sg >> 2, g = sg & 3;
  int tid = threadIdx.x;
  int w = tid >> 6, l = tid & 63;
  int p = w >> 1, sl = w & 1;
  int lg = l >> 4, li = l & 15;
  const float* Wk = d ? Wk_b : Wk_f;
  const float* Wr = d ? Wr_b : Wr_f;
  const float* bias = d ? b_b : b_f;

  int ncol0 = 256 * (2 * p) + 32 * q8 + 16 * sl + li;  // gate 2p column
  int ncol1 = ncol0 + 256;                             // gate 2p+1

  // Register-resident split weight B-fragments (m92-verified addressing).
  half8 wkh[2][8], wkl[2][8], wrh[2][8], wrl[2][8];
#pragma unroll
  for (int kk = 0; kk < 8; ++kk) {
#pragma unroll
    for (int jj = 0; jj < 8; ++jj) {
      int k = 32 * kk + 8 * lg + jj;
      _Float16 hi, lo;
      split2(Wk[(size_t)k * 1024 + ncol0], hi, lo); wkh[0][kk][jj] = hi; wkl[0][kk][jj] = lo;
      split2(Wk[(size_t)k * 1024 + ncol1], hi, lo); wkh[1][kk][jj] = hi; wkl[1][kk][jj] = lo;
      split2(Wr[(size_t)k * 1024 + ncol0], hi, lo); wrh[0][kk][jj] = hi; wrl[0][kk][jj] = lo;
      split2(Wr[(size_t)k * 1024 + ncol1], hi, lo); wrh[1][kk][jj] = hi; wrl[1][kk][jj] = lo;
    }
  }
  float bs0 = bias[ncol0], bs1 = bias[ncol1];

  for (int i = tid; i < 16 * 264; i += 256) { ((u16*)hhi)[i] = 0; ((u16*)hlo)[i] = 0; }
  float cst[2] = {0.f, 0.f}, hst[2] = {0.f, 0.f};
  int fl_self = (sg * 8 + q8) * 16;

  // x staging: thread covers row sr, 16 cols at c0 of the 16x256 fp32 tile
  int sr = tid >> 4, c0 = (tid & 15) * 16;
  const float* xrow = x + ((size_t)(16 * g + sr) * 512) * 256 + c0;
  {
    int t0 = d ? 511 : 0;
    const float4v* xp = (const float4v*)(xrow + (size_t)t0 * 256);
    float va[16];
    *(float4v*)&va[0] = xp[0]; *(float4v*)&va[4] = xp[1];
    *(float4v*)&va[8] = xp[2]; *(float4v*)&va[12] = xp[3];
    half8 h0, h1, l0, l1;
#pragma unroll
    for (int j = 0; j < 8; ++j) {
      _Float16 hi, lo;
      split2(va[j], hi, lo);     h0[j] = hi; l0[j] = lo;
      split2(va[8 + j], hi, lo); h1[j] = hi; l1[j] = lo;
    }
    *(half8*)(void*)&xhi[0][sr][c0] = h0; *(half8*)(void*)&xhi[0][sr][c0 + 8] = h1;
    *(half8*)(void*)&xlo[0][sr][c0] = l0; *(half8*)(void*)&xlo[0][sr][c0 + 8] = l1;
  }
  __syncthreads();

  for (int ti = 0; ti < 512; ++ti) {
    int t = d ? (511 - ti) : ti;
    int buf = ti & 1;

    // issue next step's x loads + this step's mask loads early
    float4v xa0, xa1, xa2, xa3;
    if (ti < 511) {
      int tn = d ? (510 - ti) : (ti + 1);
      const float4v* xp = (const float4v*)(xrow + (size_t)tn * 256);
      xa0 = xp[0]; xa1 = xp[1]; xa2 = xp[2]; xa3 = xp[3];
    }
    int m0 = 2 * (tid >> 5);
    int mk0 = mask[t * 64 + 16 * g + m0];
    int mk1 = mask[t * 64 + 16 * g + m0 + 1];

    // phase A: z = b + x@Wk (split), independent of partner exchange
    float4v zm0 = {bs0, bs0, bs0, bs0}, zm1 = {bs1, bs1, bs1, bs1};
    float4v zc0 = {0.f, 0.f, 0.f, 0.f}, zc1 = {0.f, 0.f, 0.f, 0.f};
#pragma unroll
    for (int kk = 0; kk < 8; ++kk) {
      half8 axh = *(const half8*)(const void*)&xhi[buf][li][32 * kk + 8 * lg];
      half8 axl = *(const half8*)(const void*)&xlo[buf][li][32 * kk + 8 * lg];
      zm0 = __builtin_amdgcn_mfma_f32_16x16x32_f16(axh, wkh[0][kk], zm0, 0, 0, 0);
      zc0 = __builtin_amdgcn_mfma_f32_16x16x32_f16(axh, wkl[0][kk], zc0, 0, 0, 0);
      zc0 = __builtin_amdgcn_mfma_f32_16x16x32_f16(axl, wkh[0][kk], zc0, 0, 0, 0);
      zm1 = __builtin_amdgcn_mfma_f32_16x16x32_f16(axh, wkh[1][kk], zm1, 0, 0, 0);
      zc1 = __builtin_amdgcn_mfma_f32_16x16x32_f16(axh, wkl[1][kk], zc1, 0, 0, 0);
      zc1 = __builtin_amdgcn_mfma_f32_16x16x32_f16(axl, wkh[1][kk], zc1, 0, 0, 0);
    }

    // phase B: fetch partners' h(ti-1). 32-thread group per partner; every
    // reading thread does its own acquire-spin (orders + invalidates), then
    // plain vector loads (ordered after the acquire).
    if (ti > 0 && tid < 224) {
      int pi = tid >> 5, r = tid & 31;
      int qq = (q8 + 1 + pi) & 7;
      const int* fp = flags + (sg * 8 + qq) * 16;
      while (__hip_atomic_load(fp, __ATOMIC_ACQUIRE, __HIP_MEMORY_SCOPE_AGENT) < ti)
        __builtin_amdgcn_s_sleep(1);
      int m = r >> 1, cc = 16 * (r & 1);
      int slot2 = (ti - 1) & 1;
      const float* hp =
          hx + ((((size_t)(slot2 * 2 + d) * 4 + g) * 8 + qq) * 16 + m) * 32 + cc;
      float vb[16];
      *(float4v*)&vb[0] = *(const float4v*)(hp + 0);
      *(float4v*)&vb[4] = *(const float4v*)(hp + 4);
      *(float4v*)&vb[8] = *(const float4v*)(hp + 8);
      *(float4v*)&vb[12] = *(const float4v*)(hp + 12);
      half8 h0, h1, l0, l1;
#pragma unroll
      for (int j = 0; j < 8; ++j) {
        _Float16 hi, lo;
        split2(vb[j], hi, lo);     h0[j] = hi; l0[j] = lo;
        split2(vb[8 + j], hi, lo); h1[j] = hi; l1[j] = lo;
      }
      *(half8*)(void*)&hhi[m][32 * qq + cc] = h0;
      *(half8*)(void*)&hhi[m][32 * qq + cc + 8] = h1;
      *(half8*)(void*)&hlo[m][32 * qq + cc] = l0;
      *(half8*)(void*)&hlo[m][32 * qq + cc + 8] = l1;
    }
    __syncthreads();  // B2: hhi/hlo complete

    // phase C: z += h @ Wr (split)
#pragma unroll
    for (int kk = 0; kk < 8; ++kk) {
      half8 ahh = *(const half8*)(const void*)&hhi[li][32 * kk + 8 * lg];
      half8 ahl = *(const half8*)(const void*)&hlo[li][32 * kk + 8 * lg];
      zm0 = __builtin_amdgcn_mfma_f32_16x16x32_f16(ahh, wrh[0][kk], zm0, 0, 0, 0);
      zc0 = __builtin_amdgcn_mfma_f32_16x16x32_f16(ahh, wrl[0][kk], zc0, 0, 0, 0);
      zc0 = __builtin_amdgcn_mfma_f32_16x16x32_f16(ahl, wrh[0][kk], zc0, 0, 0, 0);
      zm1 = __builtin_amdgcn_mfma_f32_16x16x32_f16(ahh, wrh[1][kk], zm1, 0, 0, 0);
      zc1 = __builtin_amdgcn_mfma_f32_16x16x32_f16(ahh, wrl[1][kk], zc1, 0, 0, 0);
      zc1 = __builtin_amdgcn_mfma_f32_16x16x32_f16(ahl, wrh[1][kk], zc1, 0, 0, 0);
    }
#pragma unroll
    for (int rr = 0; rr < 4; ++rr) {
      zb[2 * p][4 * lg + rr][16 * sl + li] = clamp30(zm0[rr] + zc0[rr] * LO_ISCALE);
      zb[2 * p + 1][4 * lg + rr][16 * sl + li] = clamp30(zm1[rr] + zc1[rr] * LO_ISCALE);
    }

    // stage x(t+1) into the other buffer (read next iter, after B3+B4)
    if (ti < 511) {
      float va[16];
      *(float4v*)&va[0] = xa0; *(float4v*)&va[4] = xa1;
      *(float4v*)&va[8] = xa2; *(float4v*)&va[12] = xa3;
      half8 h0, h1, l0, l1;
#pragma unroll
      for (int j = 0; j < 8; ++j) {
        _Float16 hi, lo;
        split2(va[j], hi, lo);     h0[j] = hi; l0[j] = lo;
        split2(va[8 + j], hi, lo); h1[j] = hi; l1[j] = lo;
      }
      *(half8*)(void*)&xhi[buf ^ 1][sr][c0] = h0;
      *(half8*)(void*)&xhi[buf ^ 1][sr][c0 + 8] = h1;
      *(half8*)(void*)&xlo[buf ^ 1][sr][c0] = l0;
      *(half8*)(void*)&xlo[buf ^ 1][sr][c0 + 8] = l1;
    }
    __syncthreads();  // B3: zb + x stage ready

    // phase D: state update — thread owns unit-col uo, rows m0,m0+1
    int uo = tid & 31;
    int slot = ti & 1;
#pragma unroll
    for (int e2 = 0; e2 < 2; ++e2) {
      int m = m0 + e2;
      float zi = zb[0][m][uo];
      float zf = zb[1][m][uo];
      float zg = zb[2][m][uo];
      float zo = zb[3][m][uo];
      float gi = ftanh(zi), gf = ftanh(zf), gg = ftanh(zg), go = ftanh(zo);
      float cn = gf * cst[e2] + gi * gg;
      float hn = go * ftanh(cn);
      int b = 16 * g + m;
      bool mk = (e2 ? mk1 : mk0) != 0;
      cst[e2] = mk ? cn : cst[e2];
      hst[e2] = mk ? hn : hst[e2];
      float hv = hst[e2];
      _Float16 hi, lo; split2(hv, hi, lo);
      hhi[m][32 * q8 + uo] = h2u(hi);
      hlo[m][32 * q8 + uo] = h2u(lo);
      __hip_atomic_store(
          hx + ((((size_t)(slot * 2 + d) * 4 + g) * 8 + q8) * 16 + m) * 32 + uo,
          hv, __ATOMIC_RELAXED, __HIP_MEMORY_SCOPE_AGENT);
      out[((size_t)b * 512 + t) * 512 + 256 * d + 32 * q8 + uo] = hv;  // fp32 output
    }
    __syncthreads();  // B4: all waves' stores drained (vmcnt(0) before barrier)
    if (tid == 0) {
      __threadfence();  // push dirty L2 lines toward coherent point
      __hip_atomic_store(flags + fl_self, ti + 1, __ATOMIC_RELEASE, __HIP_MEMORY_SCOPE_AGENT);
    }
  }

  // state_h (fp32)
  int uo = tid & 31;
  int m0 = 2 * (tid >> 5);
#pragma unroll
  for (int e2 = 0; e2 < 2; ++e2) {
    int b = 16 * g + m0 + e2;
    out[(size_t)16777216 + (size_t)b * 512 + 256 * d + 32 * q8 + uo] = hst[e2];
  }
}

extern "C" void kernel_launch(void* const* d_in, const int* in_sizes, int n_in,
                              void* d_out, int out_size, void* d_ws, size_t ws_size,
                              hipStream_t stream) {
  const float* x    = (const float*)d_in[0];
  const float* Wk_f = (const float*)d_in[1];
  const float* Wr_f = (const float*)d_in[2];
  const float* b_f  = (const float*)d_in[3];
  const float* Wk_b = (const float*)d_in[4];
  const float* Wr_b = (const float*)d_in[5];
  const float* b_b  = (const float*)d_in[6];
  char* ws = (char*)d_ws;
  float* hx  = (float*)(ws + OFF_HX);
  int* flags = (int*)(ws + OFF_FLAGS);
  unsigned char* maskp = (unsigned char*)(ws + OFF_MASK);
  float* out = (float*)d_out;

  k_mask<<<8192, 256, 0, stream>>>(x, maskp, flags);
  k_scan<<<64, 256, 0, stream>>>(Wk_f, Wr_f, b_f, Wk_b, Wr_b, b_b, x, maskp, hx, flags, out);
}

// Round 7
// 1613.211 us; speedup vs baseline: 2.5271x; 2.5271x over previous
//
#include <hip/hip_runtime.h>

typedef _Float16 half8 __attribute__((ext_vector_type(8)));
typedef float float4v __attribute__((ext_vector_type(4)));
typedef unsigned short u16;
typedef unsigned int u32;

// ---------- workspace layout (bytes); total ~300 KB ----------
#define OFF_HX    ((size_t)0)        /* 2(slot)*2(d)*4(g)*8(q8)*16*32 floats = 262144 B */
#define OFF_FLAGS ((size_t)262144)   /* 1024 ints = 4096 B */
#define OFF_MASK  ((size_t)266240)   /* 32768 B */

#define LO_SCALE   2048.0f
#define LO_ISCALE  (1.0f / 2048.0f)

__device__ __forceinline__ u16 h2u(_Float16 h) {
  union { _Float16 h; u16 u; } u; u.h = h; return u.u;
}
__device__ __forceinline__ float ftanh(float x) {
  // tanh(x) = 1 - 2/(exp(2x)+1); exact saturation for large |x|
  float e = __expf(x + x);
  return 1.0f - 2.0f * __builtin_amdgcn_rcpf(e + 1.0f);
}
__device__ __forceinline__ float clamp30(float v) {
  // NaN-proof guard; never triggers on sane data (|z| <~ 8)
  return fminf(30.0f, fmaxf(-30.0f, v));
}
// split v = hi + lo/2048 (lo pre-scaled so it never hits f16 subnormals)
__device__ __forceinline__ void split2(float v, _Float16& hi, _Float16& lo) {
  hi = (_Float16)v;
  lo = (_Float16)((v - (float)hi) * LO_SCALE);
}

// ---------------- mask[t][b] = any(x[b,t,:] != 0); also zero flags ----------------
__global__ __launch_bounds__(256) void k_mask(const float* __restrict__ x,
                                              unsigned char* __restrict__ mask,
                                              int* __restrict__ flags) {
  if (blockIdx.x < 4) flags[blockIdx.x * 256 + threadIdx.x] = 0;
  int w = threadIdx.x >> 6, l = threadIdx.x & 63;
  int row = blockIdx.x * 4 + w;  // row = b*512 + t, 0..32767
  const float4v* p = (const float4v*)(x + (size_t)row * 256 + l * 4);
  float4v v = *p;
  int nz = (v[0] != 0.f) || (v[1] != 0.f) || (v[2] != 0.f) || (v[3] != 0.f);
  unsigned long long bal = __ballot(nz);
  if (l == 0) {
    int b = row >> 9, t = row & 511;
    mask[t * 64 + b] = (bal != 0ull) ? 1 : 0;
  }
}

// ---------------- fused sequential scan, split-f16 (fp32-grade), fp32 out ----------------
// 64 WGs: bid = q8*8 + (d*4+g): the 8 octant-WGs of a scan group share one XCD
// under round-robin bid&7 (latency heuristic only, not correctness).
// Cross-WG handoff is ALL-ATOMIC at agent scope (sc1, coherent-point ops):
//   writers: relaxed atomic hx stores -> B4 barrier drains vmcnt(0) -> relaxed flag store
//   readers: relaxed flag spin -> control-dependent relaxed 8B atomic data loads
// No fences => no buffer_wbl2 / buffer_inv on the critical path.
__global__ __launch_bounds__(256, 1) void k_scan(const float* __restrict__ Wk_f,
                                                 const float* __restrict__ Wr_f,
                                                 const float* __restrict__ b_f,
                                                 const float* __restrict__ Wk_b,
                                                 const float* __restrict__ Wr_b,
                                                 const float* __restrict__ b_b,
                                                 const float* __restrict__ x,
                                                 const unsigned char* __restrict__ mask,
                                                 float* __restrict__ hx,
                                                 int* __restrict__ flags,
                                                 float* __restrict__ out) {
  __shared__ u16 hhi[16][264], hlo[16][264];       // f16 bits, full 256 units
  __shared__ u16 xhi[2][16][264], xlo[2][16][264]; // f16 x tile, double-buffered
  __shared__ float zb[4][16][34];                  // [gate][row][unitcol+pad]

  int bid = blockIdx.x;
  int sg = bid & 7, q8 = bid >> 3;
  int d = sg >> 2, g = sg & 3;
  int tid = threadIdx.x;
  int w = tid >> 6, l = tid & 63;
  int p = w >> 1, sl = w & 1;
  int lg = l >> 4, li = l & 15;
  const float* Wk = d ? Wk_b : Wk_f;
  const float* Wr = d ? Wr_b : Wr_f;
  const float* bias = d ? b_b : b_f;

  int ncol0 = 256 * (2 * p) + 32 * q8 + 16 * sl + li;  // gate 2p column
  int ncol1 = ncol0 + 256;                             // gate 2p+1

  // Register-resident split weight B-fragments (m92-verified addressing).
  half8 wkh[2][8], wkl[2][8], wrh[2][8], wrl[2][8];
#pragma unroll
  for (int kk = 0; kk < 8; ++kk) {
#pragma unroll
    for (int jj = 0; jj < 8; ++jj) {
      int k = 32 * kk + 8 * lg + jj;
      _Float16 hi, lo;
      split2(Wk[(size_t)k * 1024 + ncol0], hi, lo); wkh[0][kk][jj] = hi; wkl[0][kk][jj] = lo;
      split2(Wk[(size_t)k * 1024 + ncol1], hi, lo); wkh[1][kk][jj] = hi; wkl[1][kk][jj] = lo;
      split2(Wr[(size_t)k * 1024 + ncol0], hi, lo); wrh[0][kk][jj] = hi; wrl[0][kk][jj] = lo;
      split2(Wr[(size_t)k * 1024 + ncol1], hi, lo); wrh[1][kk][jj] = hi; wrl[1][kk][jj] = lo;
    }
  }
  float bs0 = bias[ncol0], bs1 = bias[ncol1];

  for (int i = tid; i < 16 * 264; i += 256) { ((u16*)hhi)[i] = 0; ((u16*)hlo)[i] = 0; }
  float cst[2] = {0.f, 0.f}, hst[2] = {0.f, 0.f};
  int fl_self = (sg * 8 + q8) * 16;

  // x staging: thread covers row sr, 16 cols at c0 of the 16x256 fp32 tile
  int sr = tid >> 4, c0 = (tid & 15) * 16;
  const float* xrow = x + ((size_t)(16 * g + sr) * 512) * 256 + c0;
  {
    int t0 = d ? 511 : 0;
    const float4v* xp = (const float4v*)(xrow + (size_t)t0 * 256);
    float va[16];
    *(float4v*)&va[0] = xp[0]; *(float4v*)&va[4] = xp[1];
    *(float4v*)&va[8] = xp[2]; *(float4v*)&va[12] = xp[3];
    half8 h0, h1, l0, l1;
#pragma unroll
    for (int j = 0; j < 8; ++j) {
      _Float16 hi, lo;
      split2(va[j], hi, lo);     h0[j] = hi; l0[j] = lo;
      split2(va[8 + j], hi, lo); h1[j] = hi; l1[j] = lo;
    }
    *(half8*)(void*)&xhi[0][sr][c0] = h0; *(half8*)(void*)&xhi[0][sr][c0 + 8] = h1;
    *(half8*)(void*)&xlo[0][sr][c0] = l0; *(half8*)(void*)&xlo[0][sr][c0 + 8] = l1;
  }
  __syncthreads();

  for (int ti = 0; ti < 512; ++ti) {
    int t = d ? (511 - ti) : ti;
    int buf = ti & 1;

    // issue next step's x loads + this step's mask loads early
    float4v xa0, xa1, xa2, xa3;
    if (ti < 511) {
      int tn = d ? (510 - ti) : (ti + 1);
      const float4v* xp = (const float4v*)(xrow + (size_t)tn * 256);
      xa0 = xp[0]; xa1 = xp[1]; xa2 = xp[2]; xa3 = xp[3];
    }
    int m0 = 2 * (tid >> 5);
    int mk0 = mask[t * 64 + 16 * g + m0];
    int mk1 = mask[t * 64 + 16 * g + m0 + 1];

    // phase A: z = b + x@Wk (split), independent of partner exchange
    float4v zm0 = {bs0, bs0, bs0, bs0}, zm1 = {bs1, bs1, bs1, bs1};
    float4v zc0 = {0.f, 0.f, 0.f, 0.f}, zc1 = {0.f, 0.f, 0.f, 0.f};
#pragma unroll
    for (int kk = 0; kk < 8; ++kk) {
      half8 axh = *(const half8*)(const void*)&xhi[buf][li][32 * kk + 8 * lg];
      half8 axl = *(const half8*)(const void*)&xlo[buf][li][32 * kk + 8 * lg];
      zm0 = __builtin_amdgcn_mfma_f32_16x16x32_f16(axh, wkh[0][kk], zm0, 0, 0, 0);
      zc0 = __builtin_amdgcn_mfma_f32_16x16x32_f16(axh, wkl[0][kk], zc0, 0, 0, 0);
      zc0 = __builtin_amdgcn_mfma_f32_16x16x32_f16(axl, wkh[0][kk], zc0, 0, 0, 0);
      zm1 = __builtin_amdgcn_mfma_f32_16x16x32_f16(axh, wkh[1][kk], zm1, 0, 0, 0);
      zc1 = __builtin_amdgcn_mfma_f32_16x16x32_f16(axh, wkl[1][kk], zc1, 0, 0, 0);
      zc1 = __builtin_amdgcn_mfma_f32_16x16x32_f16(axl, wkh[1][kk], zc1, 0, 0, 0);
    }

    // phase B: fetch partners' h(ti-1). 32-thread group per partner; relaxed
    // flag spin (no cache maintenance), then relaxed 8B atomic loads (sc1 -> 
    // coherent point, ordered after flag by control dependence).
    if (ti > 0 && tid < 224) {
      int pi = tid >> 5, r = tid & 31;
      int qq = (q8 + 1 + pi) & 7;
      const int* fp = flags + (sg * 8 + qq) * 16;
      while (__hip_atomic_load(fp, __ATOMIC_RELAXED, __HIP_MEMORY_SCOPE_AGENT) < ti)
        __builtin_amdgcn_s_sleep(1);
      int m = r >> 1, cc = 16 * (r & 1);
      int slot2 = (ti - 1) & 1;
      const float* hp =
          hx + ((((size_t)(slot2 * 2 + d) * 4 + g) * 8 + qq) * 16 + m) * 32 + cc;
      float vb[16];
#pragma unroll
      for (int j = 0; j < 8; ++j) {
        double dv = __hip_atomic_load((const double*)(const void*)hp + j,
                                      __ATOMIC_RELAXED, __HIP_MEMORY_SCOPE_AGENT);
        union { double dd; float ff[2]; } uu; uu.dd = dv;
        vb[2 * j] = uu.ff[0]; vb[2 * j + 1] = uu.ff[1];
      }
      half8 h0, h1, l0, l1;
#pragma unroll
      for (int j = 0; j < 8; ++j) {
        _Float16 hi, lo;
        split2(vb[j], hi, lo);     h0[j] = hi; l0[j] = lo;
        split2(vb[8 + j], hi, lo); h1[j] = hi; l1[j] = lo;
      }
      *(half8*)(void*)&hhi[m][32 * qq + cc] = h0;
      *(half8*)(void*)&hhi[m][32 * qq + cc + 8] = h1;
      *(half8*)(void*)&hlo[m][32 * qq + cc] = l0;
      *(half8*)(void*)&hlo[m][32 * qq + cc + 8] = l1;
    }
    __syncthreads();  // B2: hhi/hlo complete

    // phase C: z += h @ Wr (split)
#pragma unroll
    for (int kk = 0; kk < 8; ++kk) {
      half8 ahh = *(const half8*)(const void*)&hhi[li][32 * kk + 8 * lg];
      half8 ahl = *(const half8*)(const void*)&hlo[li][32 * kk + 8 * lg];
      zm0 = __builtin_amdgcn_mfma_f32_16x16x32_f16(ahh, wrh[0][kk], zm0, 0, 0, 0);
      zc0 = __builtin_amdgcn_mfma_f32_16x16x32_f16(ahh, wrl[0][kk], zc0, 0, 0, 0);
      zc0 = __builtin_amdgcn_mfma_f32_16x16x32_f16(ahl, wrh[0][kk], zc0, 0, 0, 0);
      zm1 = __builtin_amdgcn_mfma_f32_16x16x32_f16(ahh, wrh[1][kk], zm1, 0, 0, 0);
      zc1 = __builtin_amdgcn_mfma_f32_16x16x32_f16(ahh, wrl[1][kk], zc1, 0, 0, 0);
      zc1 = __builtin_amdgcn_mfma_f32_16x16x32_f16(ahl, wrh[1][kk], zc1, 0, 0, 0);
    }
#pragma unroll
    for (int rr = 0; rr < 4; ++rr) {
      zb[2 * p][4 * lg + rr][16 * sl + li] = clamp30(zm0[rr] + zc0[rr] * LO_ISCALE);
      zb[2 * p + 1][4 * lg + rr][16 * sl + li] = clamp30(zm1[rr] + zc1[rr] * LO_ISCALE);
    }

    // stage x(t+1) into the other buffer (read next iter, after B3+B4)
    if (ti < 511) {
      float va[16];
      *(float4v*)&va[0] = xa0; *(float4v*)&va[4] = xa1;
      *(float4v*)&va[8] = xa2; *(float4v*)&va[12] = xa3;
      half8 h0, h1, l0, l1;
#pragma unroll
      for (int j = 0; j < 8; ++j) {
        _Float16 hi, lo;
        split2(va[j], hi, lo);     h0[j] = hi; l0[j] = lo;
        split2(va[8 + j], hi, lo); h1[j] = hi; l1[j] = lo;
      }
      *(half8*)(void*)&xhi[buf ^ 1][sr][c0] = h0;
      *(half8*)(void*)&xhi[buf ^ 1][sr][c0 + 8] = h1;
      *(half8*)(void*)&xlo[buf ^ 1][sr][c0] = l0;
      *(half8*)(void*)&xlo[buf ^ 1][sr][c0 + 8] = l1;
    }
    __syncthreads();  // B3: zb + x stage ready

    // phase D: state update — thread owns unit-col uo, rows m0,m0+1
    int uo = tid & 31;
    int slot = ti & 1;
#pragma unroll
    for (int e2 = 0; e2 < 2; ++e2) {
      int m = m0 + e2;
      float zi = zb[0][m][uo];
      float zf = zb[1][m][uo];
      float zg = zb[2][m][uo];
      float zo = zb[3][m][uo];
      float gi = ftanh(zi), gf = ftanh(zf), gg = ftanh(zg), go = ftanh(zo);
      float cn = gf * cst[e2] + gi * gg;
      float hn = go * ftanh(cn);
      int b = 16 * g + m;
      bool mk = (e2 ? mk1 : mk0) != 0;
      cst[e2] = mk ? cn : cst[e2];
      hst[e2] = mk ? hn : hst[e2];
      float hv = hst[e2];
      _Float16 hi, lo; split2(hv, hi, lo);
      hhi[m][32 * q8 + uo] = h2u(hi);
      hlo[m][32 * q8 + uo] = h2u(lo);
      __hip_atomic_store(
          hx + ((((size_t)(slot * 2 + d) * 4 + g) * 8 + q8) * 16 + m) * 32 + uo,
          hv, __ATOMIC_RELAXED, __HIP_MEMORY_SCOPE_AGENT);
      out[((size_t)b * 512 + t) * 512 + 256 * d + 32 * q8 + uo] = hv;  // fp32, cached
    }
    __syncthreads();  // B4: drains vmcnt(0) in every wave -> hx globally visible
    if (tid == 0)
      __hip_atomic_store(flags + fl_self, ti + 1, __ATOMIC_RELAXED, __HIP_MEMORY_SCOPE_AGENT);
  }

  // state_h (fp32)
  int uo = tid & 31;
  int m0 = 2 * (tid >> 5);
#pragma unroll
  for (int e2 = 0; e2 < 2; ++e2) {
    int b = 16 * g + m0 + e2;
    out[(size_t)16777216 + (size_t)b * 512 + 256 * d + 32 * q8 + uo] = hst[e2];
  }
}

extern "C" void kernel_launch(void* const* d_in, const int* in_sizes, int n_in,
                              void* d_out, int out_size, void* d_ws, size_t ws_size,
                              hipStream_t stream) {
  const float* x    = (const float*)d_in[0];
  const float* Wk_f = (const float*)d_in[1];
  const float* Wr_f = (const float*)d_in[2];
  const float* b_f  = (const float*)d_in[3];
  const float* Wk_b = (const float*)d_in[4];
  const float* Wr_b = (const float*)d_in[5];
  const float* b_b  = (const float*)d_in[6];
  char* ws = (char*)d_ws;
  float* hx  = (float*)(ws + OFF_HX);
  int* flags = (int*)(ws + OFF_FLAGS);
  unsigned char* maskp = (unsigned char*)(ws + OFF_MASK);
  float* out = (float*)d_out;

  k_mask<<<8192, 256, 0, stream>>>(x, maskp, flags);
  k_scan<<<64, 256, 0, stream>>>(Wk_f, Wr_f, b_f, Wk_b, Wr_b, b_b, x, maskp, hx, flags, out);
}